// Round 10
// baseline (46.468 us; speedup 1.0000x reference)
//
#include <hip/hip_runtime.h>
#include <hip/hip_bf16.h>

// SpatialAttention2D MFMA v9: B=2, C=64, N=4096, 4 heads x d=16, fp32 io.
// vs v8: (1) attn 8-wave blocks: qg (2 q-groups of 16) x key-quarter (4 x
//        1024 keys), KT=64, tiles 32KB exactly (comb aliased onto dead tiles)
//        -> 4 blocks/CU, 32 waves/CU = 8/SIMD (was 4) to cover dep stalls;
//        (2) qkv drops LDS: wave-uniform x -> SGPR broadcast loads, 16
//        tokens/thread (kills its LDS-pipe bound);
//        (3) lsum via VALU adds + shuffle (v5-verified), -8 VGPR for the
//        __launch_bounds__(512,8) <=64-VGPR target.

#define NTOK 4096
#define HD   16
#define BH   8
#define KT   64                // keys per stage per quarter
#define SCH  (KT/16)           // 4 chunks per stage
#define QUART 1024             // keys per quarter
#define NSTAGE (QUART/KT)      // 16

typedef __attribute__((ext_vector_type(4))) short short4v;
typedef __attribute__((ext_vector_type(4))) float float4v;
typedef __attribute__((ext_vector_type(4))) ushort ushort4v;
typedef __attribute__((ext_vector_type(2))) unsigned uint2v;

__device__ __forceinline__ ushort f2bf(float f) {
  unsigned u = __builtin_bit_cast(unsigned, f);
  u += 0x7fffu + ((u >> 16) & 1u);          // round-to-nearest-even
  return (ushort)(u >> 16);
}

__device__ __forceinline__ float fast_exp2(float x) {
#if __has_builtin(__builtin_amdgcn_exp2f)
  return __builtin_amdgcn_exp2f(x);
#else
  return exp2f(x);
#endif
}

// packed f32x4 -> bf16x4 (RNE) via v_cvt_pk_bf16_f32 (v6b-verified form)
__device__ __forceinline__ short4v pack4_bf16(float a, float b, float c, float d) {
  __hip_bfloat162 lo = __float22bfloat162_rn(make_float2(a, b));
  __hip_bfloat162 hi = __float22bfloat162_rn(make_float2(c, d));
  unsigned ulo, uhi;
  __builtin_memcpy(&ulo, &lo, 4);
  __builtin_memcpy(&uhi, &hi, 4);
  uint2v u = { ulo, uhi };
  return __builtin_bit_cast(short4v, u);
}

// ws layout in ushort elements (3 MB total)
// Qt: [bh][d][n] (transposed), Kb: [bh][n][d], Vt: [bh][d][n]
#define QB_OFF 0
#define KB_OFF ((size_t)BH*NTOK*HD)
#define VT_OFF (2*(size_t)BH*NTOK*HD)

// ---------------------------------------------------------------------------
// Kernel 1: QKV projection, LDS-free. x addresses are wave-uniform -> SGPR
// broadcast loads; weights in VGPRs (loaded once); 16 tokens per thread.
// q scaled by 0.25*log2(e), stored [d][n]; V stored [d][n]; K stored [n][d].
// ---------------------------------------------------------------------------
__global__ __launch_bounds__(192) void qkv_proj(
    const float* __restrict__ x, const float* __restrict__ w,
    const float* __restrict__ bias, ushort* __restrict__ wsu) {
  const int TOK = 16;
  int blk = blockIdx.x;            // 2 * 4096/16 = 512
  int b   = blk >> 8;
  int n0  = (blk & 255) * TOK;
  int o   = threadIdx.x;           // 0..191

  float wr[64];
  const float4* w4 = reinterpret_cast<const float4*>(w + o*64);
  #pragma unroll
  for (int i = 0; i < 16; ++i) {
    float4 tt = w4[i];
    wr[4*i+0]=tt.x; wr[4*i+1]=tt.y; wr[4*i+2]=tt.z; wr[4*i+3]=tt.w;
  }
  float bb = bias[o];

  float a[TOK];
  #pragma unroll
  for (int j = 0; j < TOK; ++j) a[j] = bb;

  // x rows are wave-uniform: same address for every thread -> scalar loads
  const float* xb = x + ((size_t)b*64)*NTOK + n0;
  #pragma unroll 4
  for (int c = 0; c < 64; ++c) {
    const float4* xc4 = reinterpret_cast<const float4*>(xb + (size_t)c*NTOK);
    float wv = wr[c];
    #pragma unroll
    for (int q4 = 0; q4 < TOK/4; ++q4) {
      float4 xv = xc4[q4];
      a[q4*4+0] = fmaf(xv.x, wv, a[q4*4+0]);
      a[q4*4+1] = fmaf(xv.y, wv, a[q4*4+1]);
      a[q4*4+2] = fmaf(xv.z, wv, a[q4*4+2]);
      a[q4*4+3] = fmaf(xv.w, wv, a[q4*4+3]);
    }
  }

  int part = o >> 6;               // 0=q,1=k,2=v
  int oo   = o & 63;
  int h    = oo >> 4;
  int dd   = oo & 15;
  int bh   = b*4 + h;
  const float QSCALE = 0.25f * 1.44269504f;

  ushort* Qt = wsu + QB_OFF;
  ushort* Kb = wsu + KB_OFF;
  ushort* Vt = wsu + VT_OFF;

  if (part == 0) {
    #pragma unroll
    for (int q4 = 0; q4 < TOK/4; ++q4) {
      ushort4v vv = { f2bf(a[q4*4+0]*QSCALE), f2bf(a[q4*4+1]*QSCALE),
                      f2bf(a[q4*4+2]*QSCALE), f2bf(a[q4*4+3]*QSCALE) };
      *(ushort4v*)(Qt + ((size_t)bh*HD + dd)*NTOK + n0 + q4*4) = vv;
    }
  } else if (part == 1) {
    #pragma unroll
    for (int j = 0; j < TOK; ++j)
      Kb[((size_t)bh*NTOK + n0 + j)*HD + dd] = f2bf(a[j]);
  } else {
    #pragma unroll
    for (int q4 = 0; q4 < TOK/4; ++q4) {
      ushort4v vv = { f2bf(a[q4*4+0]), f2bf(a[q4*4+1]),
                      f2bf(a[q4*4+2]), f2bf(a[q4*4+3]) };
      *(ushort4v*)(Vt + ((size_t)bh*HD + dd)*NTOK + n0 + q4*4) = vv;
    }
  }
}

// ---------------------------------------------------------------------------
// Kernel 2: MFMA flash attention. Grid = 8 bh x 128 qblk(32q) = 1024 blocks,
// 8 waves: wave(qg, quart) = q-group qg (16 q) x key-quarter quart (1024 k).
// Staging via global_load_lds 16B, linear LDS dest, permuted global source
// (v7/v8-verified formulas; KT=64 -> 2 GLL per K or V tile per stage).
// 32KB LDS, 4 blocks/CU = 8 waves/SIMD. Epilogue combines 4 quarters via
// comb[] aliased onto the (dead) tiles.
// ---------------------------------------------------------------------------
__global__ __launch_bounds__(512, 8) void attn_mfma(
    const ushort* __restrict__ wsu, float* __restrict__ out) {
  const ushort* Qt = wsu + QB_OFF;
  const ushort* Kb = wsu + KB_OFF;
  const ushort* Vt = wsu + VT_OFF;

  int bh   = blockIdx.x >> 7;
  int qblk = blockIdx.x & 127;
  int tid  = threadIdx.x;
  int wid  = tid >> 6;
  int lane = tid & 63;
  int lr   = lane & 15;
  int g4   = (lane >> 4) << 2;
  int qg    = wid & 1;
  int quart = wid >> 1;            // 0..3
  int qbase = qblk*32 + qg*16;

  __shared__ __align__(16) char tiles[2][4][2][2048]; // [dbuf][quart][K/V] 32KB

  const ushort* Qh = Qt + (size_t)bh*NTOK*HD;         // [d][n]
  const ushort* Kh = Kb + (size_t)bh*NTOK*HD + (size_t)quart*QUART*HD;
  const ushort* Vh = Vt + (size_t)bh*HD*NTOK + quart*QUART;

  // Q fragment (B operand): lane l holds Q[q=l&15][d=g4..g4+3] from [d][n]
  short4v qf;
  qf[0] = (short)Qh[(size_t)(g4+0)*NTOK + qbase + lr];
  qf[1] = (short)Qh[(size_t)(g4+1)*NTOK + qbase + lr];
  qf[2] = (short)Qh[(size_t)(g4+2)*NTOK + qbase + lr];
  qf[3] = (short)Qh[(size_t)(g4+3)*NTOK + qbase + lr];

  // per-lane staging source offsets (ushort elems; v7-verified):
  size_t kgoff = (size_t)((lane >> 5)*16 + (lane & 15))*HD + ((lane >> 4) & 1)*8;
  size_t vgoff = (size_t)(lane & 15)*NTOK + (lane >> 4)*8;

  // fragment read byte-offset within a tile (v7-verified)
  int loff = ((lane >> 5) << 8) + ((lane & 15) << 4) + (((lane >> 4) & 1) << 3);

  float4v acc_e = {0.f,0.f,0.f,0.f}, acc_o = {0.f,0.f,0.f,0.f};
  float le = 0.f, lo_ = 0.f;

#define GLL(g, l_) __builtin_amdgcn_global_load_lds(                        \
    (const __attribute__((address_space(1))) unsigned*)(g),                 \
    (__attribute__((address_space(3))) unsigned*)(l_), 16, 0, 0)

#define STAGE(buf, s) do {                                                  \
    if (qg == 0) {                                                          \
      const ushort* gs = Kh + (size_t)(s)*(KT*HD) + kgoff;                  \
      char* lb = &tiles[buf][quart][0][0];                                  \
      GLL(gs, lb); GLL(gs+512, lb+1024);                                    \
    } else {                                                                \
      const ushort* gs = Vh + (size_t)(s)*KT + vgoff;                       \
      char* lb = &tiles[buf][quart][1][0];                                  \
      GLL(gs, lb); GLL(gs+32, lb+1024);                                     \
    } } while (0)

#define COMPUTE(buf) do {                                                   \
    const char* kb = &tiles[buf][quart][0][0];                              \
    const char* vb = &tiles[buf][quart][1][0];                              \
    __builtin_amdgcn_s_setprio(1);                                          \
    _Pragma("unroll")                                                       \
    for (int p = 0; p < SCH/2; ++p) {                                       \
      short4v kf_e = *(const short4v*)(kb + p*1024       + loff);           \
      short4v kf_o = *(const short4v*)(kb + p*1024 + 512 + loff);           \
      short4v vf_e = *(const short4v*)(vb + p*1024       + loff);           \
      short4v vf_o = *(const short4v*)(vb + p*1024 + 512 + loff);           \
      float4v zero = {0.f,0.f,0.f,0.f};                                     \
      float4v se = __builtin_amdgcn_mfma_f32_16x16x16bf16_1k(kf_e, qf, zero, 0,0,0); \
      float4v so = __builtin_amdgcn_mfma_f32_16x16x16bf16_1k(kf_o, qf, zero, 0,0,0); \
      float pe0 = fast_exp2(se[0]), pe1 = fast_exp2(se[1]);                 \
      float pe2 = fast_exp2(se[2]), pe3 = fast_exp2(se[3]);                 \
      float po0 = fast_exp2(so[0]), po1 = fast_exp2(so[1]);                 \
      float po2 = fast_exp2(so[2]), po3 = fast_exp2(so[3]);                 \
      le  += (pe0 + pe1) + (pe2 + pe3);                                     \
      lo_ += (po0 + po1) + (po2 + po3);                                     \
      short4v pbe = pack4_bf16(pe0, pe1, pe2, pe3);                         \
      short4v pbo = pack4_bf16(po0, po1, po2, po3);                         \
      acc_e = __builtin_amdgcn_mfma_f32_16x16x16bf16_1k(vf_e, pbe, acc_e, 0,0,0); \
      acc_o = __builtin_amdgcn_mfma_f32_16x16x16bf16_1k(vf_o, pbo, acc_o, 0,0,0); \
    }                                                                       \
    __builtin_amdgcn_s_setprio(0);                                          \
    } while (0)

  // prologue: stage 0 (compiler drains vmcnt before the barrier)
  STAGE(0, 0);
  __syncthreads();

  #pragma unroll 1
  for (int s = 0; s < NSTAGE; s += 2) {
    if (s + 1 < NSTAGE) STAGE(1, s + 1);   // prefetch next stage -> buf 1
    COMPUTE(0);
    __syncthreads();
    if (s + 2 < NSTAGE) STAGE(0, s + 2);   // prefetch -> buf 0
    COMPUTE(1);
    __syncthreads();
  }
  // after the trailing sync, tiles are dead -> alias comb onto them

  // per-wave l total for q = lane&15 (lanes l^16, l^32 hold same q)
  float l = le + lo_;
  l += __shfl_xor(l, 16); l += __shfl_xor(l, 32);

  float a0 = acc_e[0] + acc_o[0];
  float a1 = acc_e[1] + acc_o[1];
  float a2 = acc_e[2] + acc_o[2];
  float a3 = acc_e[3] + acc_o[3];

  float* combp = (float*)&tiles[0][0][0][0];   // 2 qg x 3 pubs x 64 x 5 floats
  if (quart != 0) {
    float* cp = combp + (((qg*3 + (quart-1))*64 + lane)*5);
    cp[0] = a0; cp[1] = a1; cp[2] = a2; cp[3] = a3; cp[4] = l;
  }
  __syncthreads();
  if (quart == 0) {
    #pragma unroll
    for (int p2 = 0; p2 < 3; ++p2) {
      const float* cp = combp + (((qg*3 + p2)*64 + lane)*5);
      a0 += cp[0]; a1 += cp[1]; a2 += cp[2]; a3 += cp[3]; l += cp[4];
    }
    float inv = 1.0f / l;
    int b = bh >> 2, h = bh & 3;
    float* ob = out + ((size_t)(b*64 + h*16 + g4)) * NTOK;
    ob[           qbase + lr] = a0 * inv;
    ob[  NTOK   + qbase + lr] = a1 * inv;
    ob[2*NTOK   + qbase + lr] = a2 * inv;
    ob[3*NTOK   + qbase + lr] = a3 * inv;
  }
#undef GLL
#undef STAGE
#undef COMPUTE
}

extern "C" void kernel_launch(void* const* d_in, const int* in_sizes, int n_in,
                              void* d_out, int out_size, void* d_ws, size_t ws_size,
                              hipStream_t stream) {
  const float* x    = (const float*)d_in[0];   // (2,64,64,64)
  const float* w    = (const float*)d_in[1];   // (192,64)
  const float* bias = (const float*)d_in[2];   // (192,)
  float* out  = (float*)d_out;                 // (2,64,64,64)
  ushort* wsu = (ushort*)d_ws;                 // 3 MB used

  qkv_proj <<<512,  192, 0, stream>>>(x, w, bias, wsu);
  attn_mfma<<<1024, 512, 0, stream>>>(wsu, out);
}